// Round 3
// baseline (1769.440 us; speedup 1.0000x reference)
//
#include <hip/hip_runtime.h>
#include <stdint.h>

#define B_ 64
#define S_ 512
#define I_ 512
#define H_ 1024
#define O_ 512
#define HB (B_ * H_)     // 65536 elements per hs slot
#define SENT 0x7F80u     // bf16 +inf: tanh output can never equal this

typedef __attribute__((ext_vector_type(8))) short bf16x8;   // 8 bf16 in 4 VGPRs
typedef __attribute__((ext_vector_type(4))) float f32x4;

__device__ inline unsigned short f2bf(float f) {
    union { float f; unsigned u; } v; v.f = f;
    unsigned r = v.u + 0x7fffu + ((v.u >> 16) & 1u);   // RNE
    return (unsigned short)(r >> 16);
}
__device__ inline float bf2f(unsigned short h) {
    union { unsigned u; float f; } v; v.u = ((unsigned)h) << 16; return v.f;
}
// nonzero iff either 16-bit half of w equals SENT
__device__ inline unsigned sentchk(unsigned w) {
    unsigned x = w ^ 0x7F807F80u;                       // halves==0 where sentinel
    return (x - 0x00010001u) & ~x & 0x80008000u;        // has-zero-halfword idiom
}

// ---------------------------------------------------------------------------
// Tiled hs layout (bf16, S+1 slots). Element h_t[b][kk]  (b=16g+rr, rr<16):
//   slot t, element offset within slot:
//     g*16384 + (kk>>8)*4096 + ((kk>>5)&7)*512 + (((kk>>3)&3)*16 + rr)*8 + (kk&7)
// This is exactly MFMA A-fragment order for the scan: wave w of consumer block
// (g,*) polls the contiguous 8 KB at [g*16384 + w*4096], and load k's uint4 at
// unit (k*64+lane) IS the A-fragment of K-chunk k for lane (l16=lane&15,q=lane>>4).
// ---------------------------------------------------------------------------

// ---------------- fp32 -> bf16 convert (x4 vectorized) ----------------
__global__ void k_f2bf4(const float4* __restrict__ src, ushort4* __restrict__ dst, int n4) {
    int i = blockIdx.x * blockDim.x + threadIdx.x;
    if (i < n4) {
        float4 v = src[i];
        ushort4 o;
        o.x = f2bf(v.x); o.y = f2bf(v.y); o.z = f2bf(v.z); o.w = f2bf(v.w);
        dst[i] = o;
    }
}

// ---------------- init: hs slot 0 = 0 (h0), slots 1..S = sentinel ----------------
__global__ void k_init(uint4* __restrict__ hs) {
    size_t i = (size_t)blockIdx.x * blockDim.x + threadIdx.x;   // one uint4 = 8 bf16
    size_t n = (size_t)(S_ + 1) * HB / 8;
    if (i >= n) return;
    unsigned v = (i < HB / 8) ? 0u : (SENT | (SENT << 16));
    hs[i] = (uint4){v, v, v, v};
}

// ---------------- generic 128x128 bf16 MFMA GEMM: C = A(MxK) * B(NxK)^T ----------------
// MODE 0: A plain row-major; C -> xi (S,B,H) bf16 with +bias1+bias2.
// MODE 1: A = tiled hs (slots 1..S decoded per the layout above); C -> out fp32 +bias1.
template <int MODE>
__global__ __launch_bounds__(256) void k_gemm(
    const unsigned short* __restrict__ A, const unsigned short* __restrict__ Bm,
    const float* __restrict__ bias1, const float* __restrict__ bias2,
    void* __restrict__ Cout, int M, int N, int K)
{
    __shared__ unsigned short As[128][40];
    __shared__ unsigned short Bs[128][40];

    const int tid  = threadIdx.x;
    const int m0   = blockIdx.x * 128;
    const int n0   = blockIdx.y * 128;
    const int wave = tid >> 6, lane = tid & 63;
    const int wm   = (wave >> 1) * 64, wn = (wave & 1) * 64;
    const int l16  = lane & 15, q = lane >> 4;

    f32x4 acc[4][4];
#pragma unroll
    for (int a = 0; a < 4; ++a)
#pragma unroll
        for (int b = 0; b < 4; ++b)
            acc[a][b] = (f32x4){0.f, 0.f, 0.f, 0.f};

    for (int k0 = 0; k0 < K; k0 += 32) {
#pragma unroll
        for (int c = 0; c < 2; ++c) {
            int idx = tid + c * 256;
            int row = idx >> 2, col = (idx & 3) * 8;
            if (MODE == 0) {
                *(bf16x8*)&As[row][col] = *(const bf16x8*)&A[(size_t)(m0 + row) * K + k0 + col];
            } else {
                int m = m0 + row, kk = k0 + col;
                int t = m >> 6, b = m & 63;
                size_t E = (size_t)(t + 1) * 65536 + (size_t)(b >> 4) * 16384
                         + (size_t)(kk >> 8) * 4096 + (size_t)((kk >> 5) & 7) * 512
                         + (size_t)((((kk >> 3) & 3) * 16 + (b & 15)) * 8);
                *(bf16x8*)&As[row][col] = *(const bf16x8*)&A[E];
            }
            *(bf16x8*)&Bs[row][col] = *(const bf16x8*)&Bm[(size_t)(n0 + row) * K + k0 + col];
        }
        __syncthreads();

        bf16x8 af[4], bfr[4];
#pragma unroll
        for (int mt = 0; mt < 4; ++mt) af[mt]  = *(const bf16x8*)&As[wm + mt * 16 + l16][q * 8];
#pragma unroll
        for (int nt = 0; nt < 4; ++nt) bfr[nt] = *(const bf16x8*)&Bs[wn + nt * 16 + l16][q * 8];
#pragma unroll
        for (int mt = 0; mt < 4; ++mt)
#pragma unroll
            for (int nt = 0; nt < 4; ++nt)
                acc[mt][nt] = __builtin_amdgcn_mfma_f32_16x16x32_bf16(af[mt], bfr[nt], acc[mt][nt], 0, 0, 0);
        __syncthreads();
    }

    // epilogue; C/D layout: col = lane&15, row = (lane>>4)*4 + reg
#pragma unroll
    for (int mt = 0; mt < 4; ++mt) {
#pragma unroll
        for (int nt = 0; nt < 4; ++nt) {
            int gn = n0 + wn + nt * 16 + l16;
#pragma unroll
            for (int i = 0; i < 4; ++i) {
                int gm = m0 + wm + mt * 16 + q * 4 + i;
                float v = acc[mt][nt][i];
                if (MODE == 0) {
                    v += bias1[gn] + bias2[gn];
                    int bb = gm >> 9, s = gm & (S_ - 1);       // gm = b*S+s
                    ((unsigned short*)Cout)[(s * B_ + bb) * H_ + gn] = f2bf(v);
                } else {
                    v += bias1[gn];
                    int t = gm >> 6, bb = gm & (B_ - 1);        // gm = t*B+b
                    ((float*)Cout)[((bb << 9) + t) * O_ + gn] = v;
                }
            }
        }
    }
}

// ---------------- sequential scan: h_{t+1} = tanh(xi_t + h_t * Wh^T) ----------------
// 4 batch-groups x 16 col-blocks, 4 waves/block splitting K 4-ways.
//  - Wh B-fragments PINNED in 128 VGPRs/lane via asm-volatile loads: volatile-asm
//    results cannot be rematerialized, so the in-loop "memory" clobbers can no
//    longer force a per-step Wh reload (round-2 bug: VGPR_Count=108 proved the
//    compiler was re-fetching 32 KB/wave of Wh from L2 EVERY timestep).
//  - hs in fragment-tiled layout: each wave's sentinel-poll is 8 contiguous
//    lane-consecutive 1 KB dwordx4 loads whose registers ARE the MFMA A-fragments.
//  - Cross-wave K-reduction via f32x4 exchange in LDS (conflict-free b128),
//    double-buffered: ONE __syncthreads per step.
// Sentinel protocol: each 2B location transitions sentinel->value exactly once.
__global__ __launch_bounds__(256, 1) void k_scan(
    const unsigned short* __restrict__ xi,   // (S,B,H) bf16
    const unsigned short* __restrict__ Wh,   // (H,H) bf16
    unsigned short* __restrict__ hs)         // (S+1) tiled slots, 1..S = sentinel
{
    __shared__ f32x4 part[2][4][4][64];      // [buf][producer wave][tile n][lane] = 32 KiB

    const int bid = blockIdx.x;
    const int g   = bid & 3;                 // batch group: rows 16g..16g+15
    const int j   = bid >> 2;                // col block:   cols 64j..64j+63
    const int n0  = j * 64;
    const int r0  = g * 16;
    const int tid = threadIdx.x;
    const int wave = tid >> 6, lane = tid & 63;
    const int l16 = lane & 15, q = lane >> 4;
    const int kbase = wave * 256;            // this wave's K-quarter
    const int ncol  = n0 + wave * 16 + l16;  // output column this lane owns

    // ---- preload Wh B-fragments (loop-invariant), register-pinned:
    // lane (l16,q) holds Wh[n0+n*16+l16][kbase + ks*32 + q*8 .. +8]  (128 VGPRs)
    uint4 wv[4][8];
#pragma unroll
    for (int n = 0; n < 4; ++n)
#pragma unroll
        for (int ks = 0; ks < 8; ++ks) {
            const unsigned short* ap =
                &Wh[(size_t)(n0 + n * 16 + l16) * H_ + kbase + ks * 32 + q * 8];
            asm volatile("global_load_dwordx4 %0, %1, off"
                         : "=v"(wv[n][ks]) : "v"(ap));
        }
    asm volatile("s_waitcnt vmcnt(0)");
    __builtin_amdgcn_sched_barrier(0);

    // poll region for this wave: contiguous 8 KB at slot*65536 + g*16384 + wave*4096
    const size_t wavebase = (size_t)g * 16384 + (size_t)wave * 4096;

    // producer-side tiled store constants (this block writes cols 64j+16*wave+l16,
    // rows r0 + q*4 + i):
    const int c_out = (j & 3) * 2 + (wave >> 1);
    const int q_out = (wave & 1) * 2 + (l16 >> 3);
    const size_t obase = (size_t)g * 16384 + (size_t)(j >> 2) * 4096
                       + (size_t)c_out * 512 + (size_t)(q_out * 16 + q * 4) * 8 + (l16 & 7);

    for (int t = 0; t < S_; ++t) {
        // xi prefetch (plain cached loads; read-only stream; row = q*4+i, col = ncol)
        const unsigned short* xit = xi + (size_t)t * HB;
        float xiv[4];
#pragma unroll
        for (int i = 0; i < 4; ++i)
            xiv[i] = bf2f(xit[(size_t)(r0 + q * 4 + i) * H_ + ncol]);

        // poll-load this wave's A-fragments: 8 contiguous lane-consecutive 1 KB loads.
        // hv[k] IS the A-fragment for K-chunk k: lane(l16,q) = h[r0+l16][kbase+k*32+q*8..+8]
        const char* hb = (const char*)hs + 2 * ((size_t)t * 65536 + wavebase);
        uint4 hv[8];
        for (;;) {
#pragma unroll
            for (int k = 0; k < 8; ++k) {
                const char* a = hb + (size_t)(k * 64 + lane) * 16;
                asm volatile("global_load_dwordx4 %0, %1, off sc0 sc1"
                             : "=v"(hv[k]) : "v"(a));
            }
            asm volatile("s_waitcnt vmcnt(0)" ::: "memory");
            __builtin_amdgcn_sched_barrier(0);
            unsigned bad = 0;
#pragma unroll
            for (int k = 0; k < 8; ++k) {
                bad |= sentchk(hv[k].x); bad |= sentchk(hv[k].y);
                bad |= sentchk(hv[k].z); bad |= sentchk(hv[k].w);
            }
            if (__ballot(bad != 0) == 0ull) break;
        }

        // 32 MFMAs: full 16x64 output tile over this wave's K-quarter
        f32x4 acc[4];
#pragma unroll
        for (int n = 0; n < 4; ++n) acc[n] = (f32x4){0.f, 0.f, 0.f, 0.f};
#pragma unroll
        for (int ks = 0; ks < 8; ++ks) {
            bf16x8 av = __builtin_bit_cast(bf16x8, hv[ks]);
#pragma unroll
            for (int n = 0; n < 4; ++n)
                acc[n] = __builtin_amdgcn_mfma_f32_16x16x32_bf16(
                    av, __builtin_bit_cast(bf16x8, wv[n][ks]), acc[n], 0, 0, 0);
        }

        // cross-wave K-reduction in fragment layout (lane-consecutive b128,
        // conflict-free), double-buffered on t&1 -> single barrier per step.
        const int p = t & 1;
#pragma unroll
        for (int n = 0; n < 4; ++n)
            part[p][wave][n][lane] = acc[n];
        __syncthreads();

        f32x4 v = (f32x4){0.f, 0.f, 0.f, 0.f};
#pragma unroll
        for (int ws = 0; ws < 4; ++ws)
            v += part[p][ws][wave][lane];      // tile n = wave of each producer

        // epilogue: tanh (branch-free), fire-and-forget write-through stores to
        // tiled slot t+1: element obase + i*8
        const unsigned short* hdst = hs + (size_t)(t + 1) * 65536 + obase;
#pragma unroll
        for (int i = 0; i < 4; ++i) {
            float x = v[i] + xiv[i];
            float e = __expf(2.f * x);
            unsigned int h16 = f2bf(1.f - 2.f / (e + 1.f));
            const unsigned short* ap = hdst + i * 8;
            asm volatile("global_store_short %0, %1, off sc0 sc1"
                         :: "v"(ap), "v"(h16) : "memory");
        }
        // no drain: next poll's vmcnt(0) covers them; visibility is eventual
    }
}

// ---------------- h_last: tiled hs slot S -> fp32 (B,H) ----------------
__global__ void k_hlast(const unsigned short* __restrict__ hsT, float* __restrict__ out) {
    int i = blockIdx.x * blockDim.x + threadIdx.x;   // i = b*1024 + kk
    if (i >= HB) return;
    int b = i >> 10, kk = i & 1023;
    size_t E = (size_t)S_ * 65536 + (size_t)(b >> 4) * 16384
             + (size_t)(kk >> 8) * 4096 + (size_t)((kk >> 5) & 7) * 512
             + (size_t)((((kk >> 3) & 3) * 16 + (b & 15)) * 8) + (kk & 7);
    out[i] = bf2f(hsT[E]);
}

extern "C" void kernel_launch(void* const* d_in, const int* in_sizes, int n_in,
                              void* d_out, int out_size, void* d_ws, size_t ws_size,
                              hipStream_t stream) {
    const float* x  = (const float*)d_in[0];
    const float* Wi = (const float*)d_in[1];
    const float* bi = (const float*)d_in[2];
    const float* Wh = (const float*)d_in[3];
    const float* bh = (const float*)d_in[4];
    const float* Wo = (const float*)d_in[5];
    const float* bo = (const float*)d_in[6];
    float* out = (float*)d_out;

    char* p = (char*)d_ws;
    unsigned short* x_bf  = (unsigned short*)p; p += (size_t)B_ * S_ * I_ * 2;
    unsigned short* Wi_bf = (unsigned short*)p; p += (size_t)H_ * I_ * 2;
    unsigned short* Wh_bf = (unsigned short*)p; p += (size_t)H_ * H_ * 2;
    unsigned short* Wo_bf = (unsigned short*)p; p += (size_t)O_ * H_ * 2;
    unsigned short* xi    = (unsigned short*)p; p += (size_t)S_ * B_ * H_ * 2;
    unsigned short* hs    = (unsigned short*)p; p += (size_t)(S_ + 1) * HB * 2;

    int n4;
    n4 = B_ * S_ * I_ / 4;
    k_f2bf4<<<(n4 + 255) / 256, 256, 0, stream>>>((const float4*)x,  (ushort4*)x_bf,  n4);
    n4 = H_ * I_ / 4;
    k_f2bf4<<<(n4 + 255) / 256, 256, 0, stream>>>((const float4*)Wi, (ushort4*)Wi_bf, n4);
    n4 = H_ * H_ / 4;
    k_f2bf4<<<(n4 + 255) / 256, 256, 0, stream>>>((const float4*)Wh, (ushort4*)Wh_bf, n4);
    n4 = O_ * H_ / 4;
    k_f2bf4<<<(n4 + 255) / 256, 256, 0, stream>>>((const float4*)Wo, (ushort4*)Wo_bf, n4);

    // hs: slot 0 = zeros, slots 1..S = bf16 +inf sentinel (layout-independent fill)
    {
        size_t n = (size_t)(S_ + 1) * HB / 8;
        k_init<<<(unsigned)((n + 255) / 256), 256, 0, stream>>>((uint4*)hs);
    }

    // xi = x * Wi^T + bi + bh   (M=32768, N=1024, K=512)
    k_gemm<0><<<dim3(B_ * S_ / 128, H_ / 128), 256, 0, stream>>>(
        x_bf, Wi_bf, bi, bh, (void*)xi, B_ * S_, H_, I_);

    // sequential scan: 64 blocks = 4 batch-groups x 16 col-blocks, static 32 KiB LDS
    k_scan<<<64, 256, 0, stream>>>(xi, Wh_bf, hs);

    // out = hs(tiled, slots 1..S) * Wo^T + bo   (M=32768, N=512, K=1024)
    k_gemm<1><<<dim3(B_ * S_ / 128, O_ / 128), 256, 0, stream>>>(
        hs, Wo_bf, bo, nullptr, (void*)out, B_ * S_, O_, H_);

    // h_last
    k_hlast<<<(HB + 255) / 256, 256, 0, stream>>>(hs, out + (size_t)B_ * S_ * O_);
}

// Round 4
// 1522.527 us; speedup vs baseline: 1.1622x; 1.1622x over previous
//
#include <hip/hip_runtime.h>
#include <stdint.h>

#define B_ 64
#define S_ 512
#define I_ 512
#define H_ 1024
#define O_ 512
#define HB (B_ * H_)     // 65536 elements per hs slot
#define SENT 0x7F80u     // bf16 +inf: tanh output can never equal this

typedef __attribute__((ext_vector_type(8))) short bf16x8;   // 8 bf16 in 4 VGPRs
typedef __attribute__((ext_vector_type(4))) float f32x4;
typedef __attribute__((ext_vector_type(2))) unsigned uint32x2;

__device__ inline unsigned short f2bf(float f) {
    union { float f; unsigned u; } v; v.f = f;
    unsigned r = v.u + 0x7fffu + ((v.u >> 16) & 1u);   // RNE
    return (unsigned short)(r >> 16);
}
__device__ inline float bf2f(unsigned short h) {
    union { unsigned u; float f; } v; v.u = ((unsigned)h) << 16; return v.f;
}
// nonzero iff either 16-bit half of w equals SENT
__device__ inline unsigned sentchk(unsigned w) {
    unsigned x = w ^ 0x7F807F80u;                       // halves==0 where sentinel
    return (x - 0x00010001u) & ~x & 0x80008000u;        // has-zero-halfword idiom
}

// ---------------------------------------------------------------------------
// Tiled hs layout (bf16, S+1 slots). Element h_t[b][kk]  (b=16g+rr, rr<16):
//   slot t, element offset within slot:
//     g*16384 + (kk>>8)*4096 + ((kk>>5)&7)*512 + (((kk>>3)&3)*16 + rr)*8 + (kk&7)
// Consumer wave w of block (g,*) polls the contiguous 8 KB at [g*16384+w*4096];
// load k's uint4 at unit (k*64+lane) IS the MFMA A-fragment of K-chunk k.
// Producer block (g,j)'s whole 16x64 output tile is the CONTIGUOUS 2 KB at
// [g*16384 + (j>>2)*4096 + (j&3)*1024] -> published as 256 coalesced 8 B stores.
// ---------------------------------------------------------------------------

// ---------------- fp32 -> bf16 convert (x4 vectorized) ----------------
__global__ void k_f2bf4(const float4* __restrict__ src, ushort4* __restrict__ dst, int n4) {
    int i = blockIdx.x * blockDim.x + threadIdx.x;
    if (i < n4) {
        float4 v = src[i];
        ushort4 o;
        o.x = f2bf(v.x); o.y = f2bf(v.y); o.z = f2bf(v.z); o.w = f2bf(v.w);
        dst[i] = o;
    }
}

// ---------------- init: hs slot 0 = 0 (h0), slots 1..S = sentinel ----------------
__global__ void k_init(uint4* __restrict__ hs) {
    size_t i = (size_t)blockIdx.x * blockDim.x + threadIdx.x;   // one uint4 = 8 bf16
    size_t n = (size_t)(S_ + 1) * HB / 8;
    if (i >= n) return;
    unsigned v = (i < HB / 8) ? 0u : (SENT | (SENT << 16));
    hs[i] = (uint4){v, v, v, v};
}

// ---------------- generic 128x128 bf16 MFMA GEMM: C = A(MxK) * B(NxK)^T ----------------
// MODE 0: A plain row-major; C -> xi (S,B,H) bf16 with +bias1+bias2.
// MODE 1: A = tiled hs (slots 1..S decoded per the layout above); C -> out fp32 +bias1.
template <int MODE>
__global__ __launch_bounds__(256) void k_gemm(
    const unsigned short* __restrict__ A, const unsigned short* __restrict__ Bm,
    const float* __restrict__ bias1, const float* __restrict__ bias2,
    void* __restrict__ Cout, int M, int N, int K)
{
    __shared__ unsigned short As[128][40];
    __shared__ unsigned short Bs[128][40];

    const int tid  = threadIdx.x;
    const int m0   = blockIdx.x * 128;
    const int n0   = blockIdx.y * 128;
    const int wave = tid >> 6, lane = tid & 63;
    const int wm   = (wave >> 1) * 64, wn = (wave & 1) * 64;
    const int l16  = lane & 15, q = lane >> 4;

    f32x4 acc[4][4];
#pragma unroll
    for (int a = 0; a < 4; ++a)
#pragma unroll
        for (int b = 0; b < 4; ++b)
            acc[a][b] = (f32x4){0.f, 0.f, 0.f, 0.f};

    for (int k0 = 0; k0 < K; k0 += 32) {
#pragma unroll
        for (int c = 0; c < 2; ++c) {
            int idx = tid + c * 256;
            int row = idx >> 2, col = (idx & 3) * 8;
            if (MODE == 0) {
                *(bf16x8*)&As[row][col] = *(const bf16x8*)&A[(size_t)(m0 + row) * K + k0 + col];
            } else {
                int m = m0 + row, kk = k0 + col;
                int t = m >> 6, b = m & 63;
                size_t E = (size_t)(t + 1) * 65536 + (size_t)(b >> 4) * 16384
                         + (size_t)(kk >> 8) * 4096 + (size_t)((kk >> 5) & 7) * 512
                         + (size_t)((((kk >> 3) & 3) * 16 + (b & 15)) * 8);
                *(bf16x8*)&As[row][col] = *(const bf16x8*)&A[E];
            }
            *(bf16x8*)&Bs[row][col] = *(const bf16x8*)&Bm[(size_t)(n0 + row) * K + k0 + col];
        }
        __syncthreads();

        bf16x8 af[4], bfr[4];
#pragma unroll
        for (int mt = 0; mt < 4; ++mt) af[mt]  = *(const bf16x8*)&As[wm + mt * 16 + l16][q * 8];
#pragma unroll
        for (int nt = 0; nt < 4; ++nt) bfr[nt] = *(const bf16x8*)&Bs[wn + nt * 16 + l16][q * 8];
#pragma unroll
        for (int mt = 0; mt < 4; ++mt)
#pragma unroll
            for (int nt = 0; nt < 4; ++nt)
                acc[mt][nt] = __builtin_amdgcn_mfma_f32_16x16x32_bf16(af[mt], bfr[nt], acc[mt][nt], 0, 0, 0);
        __syncthreads();
    }

    // epilogue; C/D layout: col = lane&15, row = (lane>>4)*4 + reg
#pragma unroll
    for (int mt = 0; mt < 4; ++mt) {
#pragma unroll
        for (int nt = 0; nt < 4; ++nt) {
            int gn = n0 + wn + nt * 16 + l16;
#pragma unroll
            for (int i = 0; i < 4; ++i) {
                int gm = m0 + wm + mt * 16 + q * 4 + i;
                float v = acc[mt][nt][i];
                if (MODE == 0) {
                    v += bias1[gn] + bias2[gn];
                    int bb = gm >> 9, s = gm & (S_ - 1);       // gm = b*S+s
                    ((unsigned short*)Cout)[(s * B_ + bb) * H_ + gn] = f2bf(v);
                } else {
                    v += bias1[gn];
                    int t = gm >> 6, bb = gm & (B_ - 1);        // gm = t*B+b
                    ((float*)Cout)[((bb << 9) + t) * O_ + gn] = v;
                }
            }
        }
    }
}

// ---------------- sequential scan: h_{t+1} = tanh(xi_t + h_t * Wh^T) ----------------
// 4 batch-groups x 16 col-blocks, 4 waves/block splitting K 4-ways.
//  - hs in fragment-tiled layout: each wave's sentinel-poll is 8 contiguous
//    lane-consecutive 1 KB dwordx4 loads whose registers ARE the MFMA A-fragments.
//  - Cross-wave K-reduction via f32x4 LDS exchange, double-buffered, ONE barrier.
//  - NEW: coalesced publish. After the barrier, thread T finalizes elements
//    [4T..4T+4) of the block's CONTIGUOUS 2 KB tiled output region (gather 16
//    floats from part[], +xi, tanh, pack) and issues ONE global_store_dwordx2
//    sc0 sc1. Replaces 1024 scattered 2-byte write-through stores per block
//    (WRITE_SIZE was 2x ideal = half-empty MALL sectors) with 256 full-line 8 B
//    stores -> attacks the store->visible latency that dominates the step.
// Sentinel protocol: each 2B location transitions sentinel->value exactly once.
__global__ __launch_bounds__(256, 1) void k_scan(
    const unsigned short* __restrict__ xi,   // (S,B,H) bf16
    const unsigned short* __restrict__ Wh,   // (H,H) bf16
    unsigned short* __restrict__ hs)         // (S+1) tiled slots, 1..S = sentinel
{
    __shared__ f32x4 part[2][4][4][64];      // [buf][producer wave][tile n][lane] = 32 KiB

    const int bid = blockIdx.x;
    const int g   = bid & 3;                 // batch group: rows 16g..16g+15
    const int j   = bid >> 2;                // col block:   cols 64j..64j+63
    const int n0  = j * 64;
    const int r0  = g * 16;
    const int tid = threadIdx.x;
    const int wave = tid >> 6, lane = tid & 63;
    const int l16 = lane & 15, q = lane >> 4;
    const int kbase = wave * 256;            // this wave's K-quarter

    // ---- preload Wh B-fragments (plain loads; any compiler refetch is L2-hit
    // and fully hidden under the poll — proven by round-3 null result):
    // lane (l16,q) holds Wh[n0+n*16+l16][kbase + ks*32 + q*8 .. +8]
    bf16x8 wreg[4][8];
#pragma unroll
    for (int n = 0; n < 4; ++n)
#pragma unroll
        for (int ks = 0; ks < 8; ++ks)
            wreg[n][ks] = *(const bf16x8*)&Wh[(size_t)(n0 + n * 16 + l16) * H_ + kbase + ks * 32 + q * 8];

    // poll region for this wave: contiguous 8 KB at slot*65536 + g*16384 + wave*4096
    const size_t wavebase = (size_t)g * 16384 + (size_t)wave * 4096;

    // ---- output-finalize constants: thread T owns elements [4T..4T+4) of the
    // block's contiguous 1024-element region. Inverse of the tiled mapping:
    //   e = 4T+c ; c_rel=e>>9 ; u=(e>>3)&63 = qo*16+qq*4+ii ; cc=e&7
    //   producer wave n=(c_rel<<1)|(qo>>1) ; lane=(qq<<4)|((qo&1)<<3)|cc
    //   value = sum_ws part[ws][n][lane][ii]   (verified bijection)
    const int c_rel = tid >> 7;
    const int u  = (tid >> 1) & 63;
    const int qo = u >> 4, qq = (u >> 2) & 3, ii = u & 3;
    const int nn = (c_rel << 1) | (qo >> 1);
    const int lb = (qq << 4) | ((qo & 1) << 3) | ((tid & 1) << 2);   // lane of c=0
    const int row  = qq * 4 + ii;                                     // row in group
    const int colb = n0 + nn * 16 + ((qo & 1) << 3) + ((tid & 1) << 2); // col of c=0
    const size_t regbase = (size_t)g * 16384 + (size_t)(j >> 2) * 4096
                         + (size_t)(j & 3) * 1024;                    // block's 2KB region

    for (int t = 0; t < S_; ++t) {
        // xi prefetch: ONE 8 B load per thread (4 consecutive bf16 of one row)
        uint32x2 xv = *(const uint32x2*)&xi[(size_t)t * HB + (size_t)(r0 + row) * H_ + colb];

        // poll-load this wave's A-fragments: 8 contiguous lane-consecutive 1 KB loads.
        // hv[k] IS the A-fragment for K-chunk k: lane(l16,q) = h[r0+l16][kbase+k*32+q*8..+8]
        const char* hb = (const char*)hs + 2 * ((size_t)t * 65536 + wavebase);
        uint4 hv[8];
        for (;;) {
#pragma unroll
            for (int k = 0; k < 8; ++k) {
                const char* a = hb + (size_t)(k * 64 + lane) * 16;
                asm volatile("global_load_dwordx4 %0, %1, off sc0 sc1"
                             : "=v"(hv[k]) : "v"(a));
            }
            asm volatile("s_waitcnt vmcnt(0)" ::: "memory");
            __builtin_amdgcn_sched_barrier(0);
            unsigned bad = 0;
#pragma unroll
            for (int k = 0; k < 8; ++k) {
                bad |= sentchk(hv[k].x); bad |= sentchk(hv[k].y);
                bad |= sentchk(hv[k].z); bad |= sentchk(hv[k].w);
            }
            if (__ballot(bad != 0) == 0ull) break;
        }

        // 32 MFMAs: full 16x64 output tile over this wave's K-quarter
        f32x4 acc[4];
#pragma unroll
        for (int n = 0; n < 4; ++n) acc[n] = (f32x4){0.f, 0.f, 0.f, 0.f};
#pragma unroll
        for (int ks = 0; ks < 8; ++ks) {
            bf16x8 av = __builtin_bit_cast(bf16x8, hv[ks]);
#pragma unroll
            for (int n = 0; n < 4; ++n)
                acc[n] = __builtin_amdgcn_mfma_f32_16x16x32_bf16(av, wreg[n][ks], acc[n], 0, 0, 0);
        }

        // cross-wave K-reduction exchange (lane-consecutive b128, conflict-free),
        // double-buffered on t&1 -> single barrier per step.
        const int p = t & 1;
#pragma unroll
        for (int n = 0; n < 4; ++n)
            part[p][wave][n][lane] = acc[n];
        __syncthreads();

        // gather-finalize: 16 scalar LDS reads, sum over producer waves
        float s[4] = {0.f, 0.f, 0.f, 0.f};
#pragma unroll
        for (int ws = 0; ws < 4; ++ws) {
            const float* pp = (const float*)&part[p][ws][nn][lb];
#pragma unroll
            for (int c = 0; c < 4; ++c)
                s[c] += pp[c * 4 + ii];
        }

        // +xi, tanh (branch-free), pack 4 bf16 -> one coalesced 8 B store
        float xf[4] = { bf2f((unsigned short)(xv[0] & 0xffffu)),
                        bf2f((unsigned short)(xv[0] >> 16)),
                        bf2f((unsigned short)(xv[1] & 0xffffu)),
                        bf2f((unsigned short)(xv[1] >> 16)) };
        unsigned short h16[4];
#pragma unroll
        for (int c = 0; c < 4; ++c) {
            float x = s[c] + xf[c];
            float e = __expf(2.f * x);
            h16[c] = f2bf(1.f - 2.f / (e + 1.f));
        }
        uint32x2 val;
        val[0] = (unsigned)h16[0] | ((unsigned)h16[1] << 16);
        val[1] = (unsigned)h16[2] | ((unsigned)h16[3] << 16);
        const unsigned short* ap = hs + (size_t)(t + 1) * 65536 + regbase + (size_t)tid * 4;
        asm volatile("global_store_dwordx2 %0, %1, off sc0 sc1"
                     :: "v"(ap), "v"(val) : "memory");
        // no drain: next poll's vmcnt(0) covers it; visibility is eventual
    }
}

// ---------------- h_last: tiled hs slot S -> fp32 (B,H) ----------------
__global__ void k_hlast(const unsigned short* __restrict__ hsT, float* __restrict__ out) {
    int i = blockIdx.x * blockDim.x + threadIdx.x;   // i = b*1024 + kk
    if (i >= HB) return;
    int b = i >> 10, kk = i & 1023;
    size_t E = (size_t)S_ * 65536 + (size_t)(b >> 4) * 16384
             + (size_t)(kk >> 8) * 4096 + (size_t)((kk >> 5) & 7) * 512
             + (size_t)((((kk >> 3) & 3) * 16 + (b & 15)) * 8) + (kk & 7);
    out[i] = bf2f(hsT[E]);
}

extern "C" void kernel_launch(void* const* d_in, const int* in_sizes, int n_in,
                              void* d_out, int out_size, void* d_ws, size_t ws_size,
                              hipStream_t stream) {
    const float* x  = (const float*)d_in[0];
    const float* Wi = (const float*)d_in[1];
    const float* bi = (const float*)d_in[2];
    const float* Wh = (const float*)d_in[3];
    const float* bh = (const float*)d_in[4];
    const float* Wo = (const float*)d_in[5];
    const float* bo = (const float*)d_in[6];
    float* out = (float*)d_out;

    char* p = (char*)d_ws;
    unsigned short* x_bf  = (unsigned short*)p; p += (size_t)B_ * S_ * I_ * 2;
    unsigned short* Wi_bf = (unsigned short*)p; p += (size_t)H_ * I_ * 2;
    unsigned short* Wh_bf = (unsigned short*)p; p += (size_t)H_ * H_ * 2;
    unsigned short* Wo_bf = (unsigned short*)p; p += (size_t)O_ * H_ * 2;
    unsigned short* xi    = (unsigned short*)p; p += (size_t)S_ * B_ * H_ * 2;
    unsigned short* hs    = (unsigned short*)p; p += (size_t)(S_ + 1) * HB * 2;

    int n4;
    n4 = B_ * S_ * I_ / 4;
    k_f2bf4<<<(n4 + 255) / 256, 256, 0, stream>>>((const float4*)x,  (ushort4*)x_bf,  n4);
    n4 = H_ * I_ / 4;
    k_f2bf4<<<(n4 + 255) / 256, 256, 0, stream>>>((const float4*)Wi, (ushort4*)Wi_bf, n4);
    n4 = H_ * H_ / 4;
    k_f2bf4<<<(n4 + 255) / 256, 256, 0, stream>>>((const float4*)Wh, (ushort4*)Wh_bf, n4);
    n4 = O_ * H_ / 4;
    k_f2bf4<<<(n4 + 255) / 256, 256, 0, stream>>>((const float4*)Wo, (ushort4*)Wo_bf, n4);

    // hs: slot 0 = zeros, slots 1..S = bf16 +inf sentinel (layout-independent fill)
    {
        size_t n = (size_t)(S_ + 1) * HB / 8;
        k_init<<<(unsigned)((n + 255) / 256), 256, 0, stream>>>((uint4*)hs);
    }

    // xi = x * Wi^T + bi + bh   (M=32768, N=1024, K=512)
    k_gemm<0><<<dim3(B_ * S_ / 128, H_ / 128), 256, 0, stream>>>(
        x_bf, Wi_bf, bi, bh, (void*)xi, B_ * S_, H_, I_);

    // sequential scan: 64 blocks = 4 batch-groups x 16 col-blocks, static 32 KiB LDS
    k_scan<<<64, 256, 0, stream>>>(xi, Wh_bf, hs);

    // out = hs(tiled, slots 1..S) * Wo^T + bo   (M=32768, N=512, K=1024)
    k_gemm<1><<<dim3(B_ * S_ / 128, O_ / 128), 256, 0, stream>>>(
        hs, Wo_bf, bo, nullptr, (void*)out, B_ * S_, O_, H_);

    // h_last
    k_hlast<<<(HB + 255) / 256, 256, 0, stream>>>(hs, out + (size_t)B_ * S_ * O_);
}

// Round 5
// 1250.928 us; speedup vs baseline: 1.4145x; 1.2171x over previous
//
#include <hip/hip_runtime.h>
#include <stdint.h>

#define B_ 64
#define S_ 512
#define I_ 512
#define H_ 1024
#define O_ 512
#define HB (B_ * H_)     // 65536 elements per hs slot
#define SENT 0x7F80u     // bf16 +inf: tanh output can never equal this

typedef __attribute__((ext_vector_type(8))) short bf16x8;   // 8 bf16 in 4 VGPRs
typedef __attribute__((ext_vector_type(4))) float f32x4;
typedef __attribute__((ext_vector_type(2))) unsigned uint32x2;

__device__ inline unsigned short f2bf(float f) {
    union { float f; unsigned u; } v; v.f = f;
    unsigned r = v.u + 0x7fffu + ((v.u >> 16) & 1u);   // RNE
    return (unsigned short)(r >> 16);
}
__device__ inline float bf2f(unsigned short h) {
    union { unsigned u; float f; } v; v.u = ((unsigned)h) << 16; return v.f;
}

// ---------------------------------------------------------------------------
// Tiled hs layout (bf16, S+1 slots). Element h_t[b][kk]  (b=16g+rr, rr<16):
//   slot t, element offset within slot:
//     g*16384 + (kk>>8)*4096 + ((kk>>5)&7)*512 + (((kk>>3)&3)*16 + rr)*8 + (kk&7)
// Consumer wave w of block (g,*) polls the contiguous 8 KB at [g*16384+w*4096];
// load k's uint4 at unit (k*64+lane) IS the MFMA A-fragment of K-chunk k.
// Producer block (g,j)'s whole 16x64 output tile is the CONTIGUOUS 2 KB at
// [g*16384 + (j>>2)*4096 + (j&3)*1024] -> published as 256 coalesced 8 B stores.
//
// Sentinel detection shortcut: hs only ever holds 0.0, tanh outputs (|v|<=1 ->
// bf16 bit14 clear) or the sentinel 0x7F80 (bit14 SET). "any sentinel" ==
// OR of all dwords has bit 0x4000 in either half. 1 VALU op/dword.
// ---------------------------------------------------------------------------

// ---------------- fp32 -> bf16 convert (x4 vectorized) ----------------
__global__ void k_f2bf4(const float4* __restrict__ src, ushort4* __restrict__ dst, int n4) {
    int i = blockIdx.x * blockDim.x + threadIdx.x;
    if (i < n4) {
        float4 v = src[i];
        ushort4 o;
        o.x = f2bf(v.x); o.y = f2bf(v.y); o.z = f2bf(v.z); o.w = f2bf(v.w);
        dst[i] = o;
    }
}

// ---------------- init: hs slot 0 = 0 (h0), slots 1..S = sentinel ----------------
__global__ void k_init(uint4* __restrict__ hs) {
    size_t i = (size_t)blockIdx.x * blockDim.x + threadIdx.x;   // one uint4 = 8 bf16
    size_t n = (size_t)(S_ + 1) * HB / 8;
    if (i >= n) return;
    unsigned v = (i < HB / 8) ? 0u : (SENT | (SENT << 16));
    hs[i] = (uint4){v, v, v, v};
}

// ---------------- generic 128x128 bf16 MFMA GEMM: C = A(MxK) * B(NxK)^T ----------------
// MODE 0: A plain row-major; C -> xi (S,B,H) bf16 with +bias1+bias2.
// MODE 1: A = tiled hs (slots 1..S decoded per the layout above); C -> out fp32 +bias1.
template <int MODE>
__global__ __launch_bounds__(256) void k_gemm(
    const unsigned short* __restrict__ A, const unsigned short* __restrict__ Bm,
    const float* __restrict__ bias1, const float* __restrict__ bias2,
    void* __restrict__ Cout, int M, int N, int K)
{
    __shared__ unsigned short As[128][40];
    __shared__ unsigned short Bs[128][40];

    const int tid  = threadIdx.x;
    const int m0   = blockIdx.x * 128;
    const int n0   = blockIdx.y * 128;
    const int wave = tid >> 6, lane = tid & 63;
    const int wm   = (wave >> 1) * 64, wn = (wave & 1) * 64;
    const int l16  = lane & 15, q = lane >> 4;

    f32x4 acc[4][4];
#pragma unroll
    for (int a = 0; a < 4; ++a)
#pragma unroll
        for (int b = 0; b < 4; ++b)
            acc[a][b] = (f32x4){0.f, 0.f, 0.f, 0.f};

    for (int k0 = 0; k0 < K; k0 += 32) {
#pragma unroll
        for (int c = 0; c < 2; ++c) {
            int idx = tid + c * 256;
            int row = idx >> 2, col = (idx & 3) * 8;
            if (MODE == 0) {
                *(bf16x8*)&As[row][col] = *(const bf16x8*)&A[(size_t)(m0 + row) * K + k0 + col];
            } else {
                int m = m0 + row, kk = k0 + col;
                int t = m >> 6, b = m & 63;
                size_t E = (size_t)(t + 1) * 65536 + (size_t)(b >> 4) * 16384
                         + (size_t)(kk >> 8) * 4096 + (size_t)((kk >> 5) & 7) * 512
                         + (size_t)((((kk >> 3) & 3) * 16 + (b & 15)) * 8);
                *(bf16x8*)&As[row][col] = *(const bf16x8*)&A[E];
            }
            *(bf16x8*)&Bs[row][col] = *(const bf16x8*)&Bm[(size_t)(n0 + row) * K + k0 + col];
        }
        __syncthreads();

        bf16x8 af[4], bfr[4];
#pragma unroll
        for (int mt = 0; mt < 4; ++mt) af[mt]  = *(const bf16x8*)&As[wm + mt * 16 + l16][q * 8];
#pragma unroll
        for (int nt = 0; nt < 4; ++nt) bfr[nt] = *(const bf16x8*)&Bs[wn + nt * 16 + l16][q * 8];
#pragma unroll
        for (int mt = 0; mt < 4; ++mt)
#pragma unroll
            for (int nt = 0; nt < 4; ++nt)
                acc[mt][nt] = __builtin_amdgcn_mfma_f32_16x16x32_bf16(af[mt], bfr[nt], acc[mt][nt], 0, 0, 0);
        __syncthreads();
    }

    // epilogue; C/D layout: col = lane&15, row = (lane>>4)*4 + reg
#pragma unroll
    for (int mt = 0; mt < 4; ++mt) {
#pragma unroll
        for (int nt = 0; nt < 4; ++nt) {
            int gn = n0 + wn + nt * 16 + l16;
#pragma unroll
            for (int i = 0; i < 4; ++i) {
                int gm = m0 + wm + mt * 16 + q * 4 + i;
                float v = acc[mt][nt][i];
                if (MODE == 0) {
                    v += bias1[gn] + bias2[gn];
                    int bb = gm >> 9, s = gm & (S_ - 1);       // gm = b*S+s
                    ((unsigned short*)Cout)[(s * B_ + bb) * H_ + gn] = f2bf(v);
                } else {
                    v += bias1[gn];
                    int t = gm >> 6, bb = gm & (B_ - 1);        // gm = t*B+b
                    ((float*)Cout)[((bb << 9) + t) * O_ + gn] = v;
                }
            }
        }
    }
}

// ---------------- sequential scan: h_{t+1} = tanh(xi_t + h_t * Wh^T) ----------------
// 4 batch-groups x 16 col-blocks, 4 waves/block splitting K 4-ways.
//  - hs in fragment-tiled layout: each wave's sentinel-poll is 8 contiguous
//    lane-consecutive 1 KB dwordx4 loads whose registers ARE the MFMA A-fragments.
//  - Poll check: bit-14 OR trick (1 op/dword vs 6) — tanh outputs never set
//    bf16 bit14; sentinel does. ~315 cy/iteration saved inside the serial poll.
//  - Cross-wave K-reduction via f32x4 LDS exchange, double-buffered, ONE barrier.
//  - Gather-finalize bank-conflict-free: c-loop XOR-swizzled by qq (banks
//    (tid&1)*16 + (c^qq)*4 + ii = 32 distinct, 2-way aliasing = free), then a
//    static cndmask butterfly un-permutes the 4 sums (no runtime reg indexing).
//  - Coalesced publish: one global_store_dwordx2 per thread into the block's
//    contiguous 2 KB tiled region.
// Sentinel protocol: each 2B location transitions sentinel->value exactly once.
__global__ __launch_bounds__(256, 1) void k_scan(
    const unsigned short* __restrict__ xi,   // (S,B,H) bf16
    const unsigned short* __restrict__ Wh,   // (H,H) bf16
    unsigned short* __restrict__ hs)         // (S+1) tiled slots, 1..S = sentinel
{
    __shared__ f32x4 part[2][4][4][64];      // [buf][producer wave][tile n][lane] = 32 KiB

    const int bid = blockIdx.x;
    const int g   = bid & 3;                 // batch group: rows 16g..16g+15
    const int j   = bid >> 2;                // col block:   cols 64j..64j+63
    const int n0  = j * 64;
    const int r0  = g * 16;
    const int tid = threadIdx.x;
    const int wave = tid >> 6, lane = tid & 63;
    const int l16 = lane & 15, q = lane >> 4;
    const int kbase = wave * 256;            // this wave's K-quarter

    // ---- preload Wh B-fragments (plain loads; any compiler refetch is L2-hit
    // and hidden under the poll — proven by round-3 null result):
    // lane (l16,q) holds Wh[n0+n*16+l16][kbase + ks*32 + q*8 .. +8]
    bf16x8 wreg[4][8];
#pragma unroll
    for (int n = 0; n < 4; ++n)
#pragma unroll
        for (int ks = 0; ks < 8; ++ks)
            wreg[n][ks] = *(const bf16x8*)&Wh[(size_t)(n0 + n * 16 + l16) * H_ + kbase + ks * 32 + q * 8];

    // poll region for this wave: contiguous 8 KB at slot*65536 + g*16384 + wave*4096
    const size_t wavebase = (size_t)g * 16384 + (size_t)wave * 4096;

    // ---- output-finalize constants: thread T owns elements [4T..4T+4) of the
    // block's contiguous 1024-element region. Inverse of the tiled mapping:
    //   e = 4T+c ; c_rel=e>>9 ; u=(e>>3)&63 = qo*16+qq*4+ii ; cc=e&7
    //   producer wave n=(c_rel<<1)|(qo>>1) ; lane=(qq<<4)|((qo&1)<<3)|cc
    //   value = sum_ws part[ws][n][lane][ii]   (verified bijection)
    const int c_rel = tid >> 7;
    const int u  = (tid >> 1) & 63;
    const int qo = u >> 4, qq = (u >> 2) & 3, ii = u & 3;
    const int nn = (c_rel << 1) | (qo >> 1);
    const int lb = (qq << 4) | ((qo & 1) << 3) | ((tid & 1) << 2);   // lane of c=0
    const int row  = qq * 4 + ii;                                     // row in group
    const int colb = n0 + nn * 16 + ((qo & 1) << 3) + ((tid & 1) << 2); // col of c=0
    const size_t regbase = (size_t)g * 16384 + (size_t)(j >> 2) * 4096
                         + (size_t)(j & 3) * 1024;                    // block's 2KB region

    for (int t = 0; t < S_; ++t) {
        // xi prefetch: ONE 8 B load per thread (4 consecutive bf16 of one row)
        uint32x2 xv = *(const uint32x2*)&xi[(size_t)t * HB + (size_t)(r0 + row) * H_ + colb];

        // poll-load this wave's A-fragments: 8 contiguous lane-consecutive 1 KB loads.
        // hv[k] IS the A-fragment for K-chunk k: lane(l16,q) = h[r0+l16][kbase+k*32+q*8..+8]
        const char* hb = (const char*)hs + 2 * ((size_t)t * 65536 + wavebase);
        uint4 hv[8];
        for (;;) {
#pragma unroll
            for (int k = 0; k < 8; ++k) {
                const char* a = hb + (size_t)(k * 64 + lane) * 16;
                asm volatile("global_load_dwordx4 %0, %1, off sc0 sc1"
                             : "=v"(hv[k]) : "v"(a));
            }
            asm volatile("s_waitcnt vmcnt(0)" ::: "memory");
            __builtin_amdgcn_sched_barrier(0);
            // bit14-OR sentinel test: reals (tanh, 0.0) never set 0x4000 in a
            // bf16 half; sentinel 0x7F80 does.
            unsigned acc_or = 0;
#pragma unroll
            for (int k = 0; k < 8; ++k)
                acc_or |= (hv[k].x | hv[k].y) | (hv[k].z | hv[k].w);
            if (__ballot((acc_or & 0x40004000u) != 0u) == 0ull) break;
        }

        // 32 MFMAs: full 16x64 output tile over this wave's K-quarter
        f32x4 acc[4];
#pragma unroll
        for (int n = 0; n < 4; ++n) acc[n] = (f32x4){0.f, 0.f, 0.f, 0.f};
#pragma unroll
        for (int ks = 0; ks < 8; ++ks) {
            bf16x8 av = __builtin_bit_cast(bf16x8, hv[ks]);
#pragma unroll
            for (int n = 0; n < 4; ++n)
                acc[n] = __builtin_amdgcn_mfma_f32_16x16x32_bf16(av, wreg[n][ks], acc[n], 0, 0, 0);
        }

        // cross-wave K-reduction exchange (lane-consecutive b128, conflict-free),
        // double-buffered on t&1 -> single barrier per step.
        const int p = t & 1;
#pragma unroll
        for (int n = 0; n < 4; ++n)
            part[p][wave][n][lane] = acc[n];
        __syncthreads();

        // gather-finalize, bank-conflict-free: instruction slot c reads element
        // (c^qq) -> banks (tid&1)*16 + (c^qq)*4 + ii cover all 32, 2-way max.
        // s2[c] holds element (c^qq); butterfly below restores order.
        float s2[4] = {0.f, 0.f, 0.f, 0.f};
#pragma unroll
        for (int ws = 0; ws < 4; ++ws) {
            const float* pp = (const float*)&part[p][ws][nn][lb];
#pragma unroll
            for (int c = 0; c < 4; ++c)
                s2[c] += pp[((c ^ qq) << 2) + ii];
        }
        // un-butterfly: element e = s2[e ^ qq]  (static cndmask network)
        const bool b0 = (qq & 1) != 0, b1 = (qq & 2) != 0;
        float t0 = b0 ? s2[1] : s2[0], t1 = b0 ? s2[0] : s2[1];
        float t2 = b0 ? s2[3] : s2[2], t3 = b0 ? s2[2] : s2[3];
        float e0 = b1 ? t2 : t0, e1 = b1 ? t3 : t1;
        float e2 = b1 ? t0 : t2, e3 = b1 ? t1 : t3;
        float s[4] = { e0, e1, e2, e3 };

        // +xi, tanh (branch-free), pack 4 bf16 -> one coalesced 8 B store
        float xf[4] = { bf2f((unsigned short)(xv[0] & 0xffffu)),
                        bf2f((unsigned short)(xv[0] >> 16)),
                        bf2f((unsigned short)(xv[1] & 0xffffu)),
                        bf2f((unsigned short)(xv[1] >> 16)) };
        unsigned short h16[4];
#pragma unroll
        for (int c = 0; c < 4; ++c) {
            float x = s[c] + xf[c];
            float e = __expf(2.f * x);
            h16[c] = f2bf(1.f - 2.f / (e + 1.f));
        }
        uint32x2 val;
        val[0] = (unsigned)h16[0] | ((unsigned)h16[1] << 16);
        val[1] = (unsigned)h16[2] | ((unsigned)h16[3] << 16);
        const unsigned short* ap = hs + (size_t)(t + 1) * 65536 + regbase + (size_t)tid * 4;
        asm volatile("global_store_dwordx2 %0, %1, off sc0 sc1"
                     :: "v"(ap), "v"(val) : "memory");
        // no drain: next poll's vmcnt(0) covers it; visibility is eventual
    }
}

// ---------------- h_last: tiled hs slot S -> fp32 (B,H) ----------------
__global__ void k_hlast(const unsigned short* __restrict__ hsT, float* __restrict__ out) {
    int i = blockIdx.x * blockDim.x + threadIdx.x;   // i = b*1024 + kk
    if (i >= HB) return;
    int b = i >> 10, kk = i & 1023;
    size_t E = (size_t)S_ * 65536 + (size_t)(b >> 4) * 16384
             + (size_t)(kk >> 8) * 4096 + (size_t)((kk >> 5) & 7) * 512
             + (size_t)((((kk >> 3) & 3) * 16 + (b & 15)) * 8) + (kk & 7);
    out[i] = bf2f(hsT[E]);
}

extern "C" void kernel_launch(void* const* d_in, const int* in_sizes, int n_in,
                              void* d_out, int out_size, void* d_ws, size_t ws_size,
                              hipStream_t stream) {
    const float* x  = (const float*)d_in[0];
    const float* Wi = (const float*)d_in[1];
    const float* bi = (const float*)d_in[2];
    const float* Wh = (const float*)d_in[3];
    const float* bh = (const float*)d_in[4];
    const float* Wo = (const float*)d_in[5];
    const float* bo = (const float*)d_in[6];
    float* out = (float*)d_out;

    char* p = (char*)d_ws;
    unsigned short* x_bf  = (unsigned short*)p; p += (size_t)B_ * S_ * I_ * 2;
    unsigned short* Wi_bf = (unsigned short*)p; p += (size_t)H_ * I_ * 2;
    unsigned short* Wh_bf = (unsigned short*)p; p += (size_t)H_ * H_ * 2;
    unsigned short* Wo_bf = (unsigned short*)p; p += (size_t)O_ * H_ * 2;
    unsigned short* xi    = (unsigned short*)p; p += (size_t)S_ * B_ * H_ * 2;
    unsigned short* hs    = (unsigned short*)p; p += (size_t)(S_ + 1) * HB * 2;

    int n4;
    n4 = B_ * S_ * I_ / 4;
    k_f2bf4<<<(n4 + 255) / 256, 256, 0, stream>>>((const float4*)x,  (ushort4*)x_bf,  n4);
    n4 = H_ * I_ / 4;
    k_f2bf4<<<(n4 + 255) / 256, 256, 0, stream>>>((const float4*)Wi, (ushort4*)Wi_bf, n4);
    n4 = H_ * H_ / 4;
    k_f2bf4<<<(n4 + 255) / 256, 256, 0, stream>>>((const float4*)Wh, (ushort4*)Wh_bf, n4);
    n4 = O_ * H_ / 4;
    k_f2bf4<<<(n4 + 255) / 256, 256, 0, stream>>>((const float4*)Wo, (ushort4*)Wo_bf, n4);

    // hs: slot 0 = zeros, slots 1..S = bf16 +inf sentinel (layout-independent fill)
    {
        size_t n = (size_t)(S_ + 1) * HB / 8;
        k_init<<<(unsigned)((n + 255) / 256), 256, 0, stream>>>((uint4*)hs);
    }

    // xi = x * Wi^T + bi + bh   (M=32768, N=1024, K=512)
    k_gemm<0><<<dim3(B_ * S_ / 128, H_ / 128), 256, 0, stream>>>(
        x_bf, Wi_bf, bi, bh, (void*)xi, B_ * S_, H_, I_);

    // sequential scan: 64 blocks = 4 batch-groups x 16 col-blocks, static 32 KiB LDS
    k_scan<<<64, 256, 0, stream>>>(xi, Wh_bf, hs);

    // out = hs(tiled, slots 1..S) * Wo^T + bo   (M=32768, N=512, K=1024)
    k_gemm<1><<<dim3(B_ * S_ / 128, O_ / 128), 256, 0, stream>>>(
        hs, Wo_bf, bo, nullptr, (void*)out, B_ * S_, O_, H_);

    // h_last
    k_hlast<<<(HB + 255) / 256, 256, 0, stream>>>(hs, out + (size_t)B_ * S_ * O_);
}